// Round 6
// baseline (155.602 us; speedup 1.0000x reference)
//
#include <hip/hip_runtime.h>

#define C_DIM 256
#define K_NEIGH 32
#define GRID_BLKS 1024
#define BLK_THR 256

// ---------------------------------------------------------------------------
// Fused projection + attention with a hand-rolled device-scope grid barrier.
//
// Phase 1: wave-per-node complex projection (round-1 structure), grid-stride
//          with manual next-node prefetch so the load of node i+1 is in
//          flight during node i's butterfly reduction.
// Preload: each thread loads its column's 33 indices (non-temporal) BEFORE
//          the barrier — overlaps the idx stream with proj's BW-bound tail.
// Barrier: block-t0 release-fence + agent atomicAdd + spin + acquire-fence.
//          1024 blocks @ __launch_bounds__(256,4) = 4 blocks/CU co-resident
//          on 256 CUs -> spin cannot deadlock. Counter zeroed per call via
//          hipMemsetAsync (graph-capturable).
// Phase 2: thread-per-column attention, indices already in registers,
//          non-temporal output stores.
// ---------------------------------------------------------------------------
__global__ __launch_bounds__(BLK_THR, 4) void fused_kernel(
    const float* __restrict__ whr, const float* __restrict__ whi,
    const int*   __restrict__ nneg,
    const float* __restrict__ wr,  const float* __restrict__ wi,
    const float* __restrict__ br,  const float* __restrict__ bi,
    float2* __restrict__ tmp, unsigned int* __restrict__ bar,
    float* __restrict__ out, int n_nodes, int m_cols)
{
    const int gtid   = blockIdx.x * BLK_THR + threadIdx.x;
    const int gsz    = GRID_BLKS * BLK_THR;       // 262144 threads
    const int lane   = threadIdx.x & 63;
    const int wave   = gtid >> 6;                 // 0..4095
    const int nwaves = gsz >> 6;                  // 4096

    // ---- Phase 1: projection, one node per wave-iteration, prefetched.
    {
        const float4 u  = ((const float4*)wr)[lane];   // 1 KB, L1-resident
        const float4 v  = ((const float4*)wi)[lane];
        const float br0 = br[0];
        const float bi0 = bi[0];

        int node = wave;
        float4 a, b;
        if (node < n_nodes) {
            a = ((const float4*)(whr + (size_t)node * C_DIM))[lane];
            b = ((const float4*)(whi + (size_t)node * C_DIM))[lane];
        }
        while (node < n_nodes) {
            const int nnode = node + nwaves;
            float4 an, bn;
            if (nnode < n_nodes) {               // prefetch next node
                an = ((const float4*)(whr + (size_t)nnode * C_DIM))[lane];
                bn = ((const float4*)(whi + (size_t)nnode * C_DIM))[lane];
            }

            float vr = a.x*u.x + a.y*u.y + a.z*u.z + a.w*u.w
                     - (b.x*v.x + b.y*v.y + b.z*v.z + b.w*v.w);
            float vi = a.x*v.x + a.y*v.y + a.z*v.z + a.w*v.w
                     +  b.x*u.x + b.y*u.y + b.z*u.z + b.w*u.w;

            #pragma unroll
            for (int off = 32; off > 0; off >>= 1) {
                vr += __shfl_xor(vr, off, 64);
                vi += __shfl_xor(vi, off, 64);
            }
            if (lane == 0) {
                tmp[node] = make_float2(vr + br0, vi + bi0);
            }

            node = nnode;
            a = an;
            b = bn;
        }
    }

    // ---- Preload this thread's column indices (independent of tmp).
    const int m = gtid;
    int cidx = 0;
    int idx[K_NEIGH];
    if (m < m_cols) {
        cidx = __builtin_nontemporal_load(&nneg[m]);
        #pragma unroll
        for (int k = 0; k < K_NEIGH; ++k) {
            idx[k] = __builtin_nontemporal_load(&nneg[(size_t)(k + 1) * m_cols + m]);
        }
    }

    // ---- Grid barrier (device scope, cross-XCD safe).
    __syncthreads();                       // block's tmp writes all issued
    if (threadIdx.x == 0) {
        __builtin_amdgcn_fence(__ATOMIC_RELEASE, "agent");   // L2 writeback
        __hip_atomic_fetch_add(bar, 1u, __ATOMIC_RELAXED, __HIP_MEMORY_SCOPE_AGENT);
        while (__hip_atomic_load(bar, __ATOMIC_RELAXED, __HIP_MEMORY_SCOPE_AGENT)
               < (unsigned)GRID_BLKS) {
            __builtin_amdgcn_s_sleep(2);
        }
        __builtin_amdgcn_fence(__ATOMIC_ACQUIRE, "agent");   // L1/L2 invalidate
    }
    __syncthreads();                       // releases whole block (same CU)

    // ---- Phase 2: attention + normalization, thread-per-column.
    if (m < m_cols) {
        const float2 c = tmp[cidx];
        float att[K_NEIGH];
        float s = 0.f;
        #pragma unroll
        for (int k = 0; k < K_NEIGH; ++k) {
            const float2 t = tmp[idx[k]];
            const float a = fmaxf(c.x * t.x + c.y * t.y, 0.f);
            att[k] = a;
            s += a;
        }
        const float r = 1.0f / (s + 0.001f);
        #pragma unroll
        for (int k = 0; k < K_NEIGH; ++k) {
            __builtin_nontemporal_store(att[k] * r, &out[(size_t)k * m_cols + m]);
        }
    }

    // Generic fallback if m_cols ever exceeds thread count (not hit at 100k).
    for (int m2 = gtid + gsz; m2 < m_cols; m2 += gsz) {
        const float2 c = tmp[nneg[m2]];
        float att[K_NEIGH];
        float s = 0.f;
        #pragma unroll
        for (int k = 0; k < K_NEIGH; ++k) {
            const float2 t = tmp[nneg[(size_t)(k + 1) * m_cols + m2]];
            const float a = fmaxf(c.x * t.x + c.y * t.y, 0.f);
            att[k] = a;
            s += a;
        }
        const float r = 1.0f / (s + 0.001f);
        #pragma unroll
        for (int k = 0; k < K_NEIGH; ++k) {
            __builtin_nontemporal_store(att[k] * r, &out[(size_t)k * m_cols + m2]);
        }
    }
}

// ---------------------------------------------------------------------------
extern "C" void kernel_launch(void* const* d_in, const int* in_sizes, int n_in,
                              void* d_out, int out_size, void* d_ws, size_t ws_size,
                              hipStream_t stream)
{
    const float* whr = (const float*)d_in[0];
    const float* whi = (const float*)d_in[1];
    const int*   nng = (const int*)d_in[2];
    // d_in[3] = k_neighbors scalar (fixed = 32)
    const float* wr  = (const float*)d_in[4];
    const float* wi  = (const float*)d_in[5];
    const float* br  = (const float*)d_in[6];
    const float* bi  = (const float*)d_in[7];

    const int n_nodes = in_sizes[0] / in_sizes[4];     // 100000
    const int m_cols  = in_sizes[2] / (K_NEIGH + 1);   // 100000

    float2* tmp = (float2*)d_ws;                       // 800 KB
    // Barrier counter just past tmp, 256B-aligned.
    const size_t coff = ((size_t)n_nodes * sizeof(float2) + 255) & ~(size_t)255;
    unsigned int* bar = (unsigned int*)((char*)d_ws + coff);

    hipMemsetAsync(bar, 0, 256, stream);               // zero counter each call

    fused_kernel<<<GRID_BLKS, BLK_THR, 0, stream>>>(
        whr, whi, nng, wr, wi, br, bi, tmp, bar, (float*)d_out,
        n_nodes, m_cols);
}

// Round 7
// 52.729 us; speedup vs baseline: 2.9510x; 2.9510x over previous
//
#include <hip/hip_runtime.h>

#define C_DIM 256
#define K_NEIGH 32

// bf16 round-to-nearest-even from f32, as a 16-bit value.
__device__ __forceinline__ unsigned bf16_rne(float x) {
    unsigned u = __float_as_uint(x);
    return (u + 0x7fffu + ((u >> 16) & 1u)) >> 16;
}

// ---------------------------------------------------------------------------
// Kernel A: complex linear projection, one 64-lane wave per node (round-1
// structure — best measured: 52.1 us total). Each lane holds 4 consecutive
// channels via float4 (16 B/lane, fully coalesced); 12-step butterfly
// reduce; lane 0 writes tmp packed as (bf16 real | bf16 imag << 16) so the
// attention gather table is 400 KB instead of 800 KB.
// ---------------------------------------------------------------------------
__global__ __launch_bounds__(256) void proj_kernel(
    const float* __restrict__ whr, const float* __restrict__ whi,
    const float* __restrict__ wr,  const float* __restrict__ wi,
    const float* __restrict__ br,  const float* __restrict__ bi,
    unsigned* __restrict__ tmp, int n_nodes)
{
    const int node = (int)((blockIdx.x * (unsigned)blockDim.x + threadIdx.x) >> 6);
    const int lane = threadIdx.x & 63;
    if (node >= n_nodes) return;

    const float4 a = ((const float4*)(whr + (size_t)node * C_DIM))[lane];
    const float4 b = ((const float4*)(whi + (size_t)node * C_DIM))[lane];
    const float4 u = ((const float4*)wr)[lane];
    const float4 v = ((const float4*)wi)[lane];

    float vr = a.x*u.x + a.y*u.y + a.z*u.z + a.w*u.w
             - (b.x*v.x + b.y*v.y + b.z*v.z + b.w*v.w);
    float vi = a.x*v.x + a.y*v.y + a.z*v.z + a.w*v.w
             +  b.x*u.x + b.y*u.y + b.z*u.z + b.w*u.w;

    #pragma unroll
    for (int off = 32; off > 0; off >>= 1) {
        vr += __shfl_xor(vr, off, 64);
        vi += __shfl_xor(vi, off, 64);
    }

    if (lane == 0) {
        const float fr = vr + br[0];
        const float fi = vi + bi[0];
        tmp[node] = bf16_rne(fr) | (bf16_rne(fi) << 16);
    }
}

// ---------------------------------------------------------------------------
// Kernel B: per-column attention + normalization, one thread per column
// (round-1 structure — best measured). Gathers are single dwords from the
// 400 KB packed table; unpack is two bit-ops (bf16 -> f32 is a 16-bit
// shift). Index loads / stores coalesced.
// ---------------------------------------------------------------------------
__global__ __launch_bounds__(256) void attn_kernel(
    const int* __restrict__ nneg, const unsigned* __restrict__ tmp,
    float* __restrict__ out, int m_cols)
{
    const int m = blockIdx.x * blockDim.x + threadIdx.x;
    if (m >= m_cols) return;

    const unsigned cp = tmp[nneg[m]];
    const float cr = __uint_as_float(cp << 16);
    const float ci = __uint_as_float(cp & 0xffff0000u);

    float att[K_NEIGH];
    float s = 0.f;
    #pragma unroll
    for (int k = 0; k < K_NEIGH; ++k) {
        const int idx = nneg[(size_t)(k + 1) * m_cols + m];
        const unsigned tp = tmp[idx];
        const float tr = __uint_as_float(tp << 16);
        const float ti = __uint_as_float(tp & 0xffff0000u);
        const float a = fmaxf(cr * tr + ci * ti, 0.f);
        att[k] = a;
        s += a;
    }

    const float r = 1.0f / (s + 0.001f);
    #pragma unroll
    for (int k = 0; k < K_NEIGH; ++k) {
        out[(size_t)k * m_cols + m] = att[k] * r;
    }
}

// ---------------------------------------------------------------------------
extern "C" void kernel_launch(void* const* d_in, const int* in_sizes, int n_in,
                              void* d_out, int out_size, void* d_ws, size_t ws_size,
                              hipStream_t stream)
{
    const float* whr = (const float*)d_in[0];
    const float* whi = (const float*)d_in[1];
    const int*   nng = (const int*)d_in[2];
    // d_in[3] = k_neighbors scalar (fixed = 32)
    const float* wr  = (const float*)d_in[4];
    const float* wi  = (const float*)d_in[5];
    const float* br  = (const float*)d_in[6];
    const float* bi  = (const float*)d_in[7];

    const int c_dim   = in_sizes[4];                 // 256
    const int n_nodes = in_sizes[0] / c_dim;         // 100000
    const int m_cols  = in_sizes[2] / (K_NEIGH + 1); // 100000

    unsigned* tmp = (unsigned*)d_ws;                 // 400 KB packed bf16x2

    // Kernel A: wave per node, 4 nodes per 256-thread block.
    const int blocksA = (n_nodes + 3) / 4;
    proj_kernel<<<blocksA, 256, 0, stream>>>(whr, whi, wr, wi, br, bi, tmp, n_nodes);

    // Kernel B: one thread per column.
    const int blocksB = (m_cols + 255) / 256;
    attn_kernel<<<blocksB, 256, 0, stream>>>(nng, tmp, (float*)d_out, m_cols);
}

// Round 8
// 52.603 us; speedup vs baseline: 2.9580x; 1.0024x over previous
//
#include <hip/hip_runtime.h>

#define C_DIM 256
#define K_NEIGH 32

// bf16 round-to-nearest-even from f32, as a 16-bit value.
__device__ __forceinline__ unsigned bf16_rne(float x) {
    unsigned u = __float_as_uint(x);
    return (u + 0x7fffu + ((u >> 16) & 1u)) >> 16;
}

// ---------------------------------------------------------------------------
// Kernel A: complex linear projection. One-shot (non-persistent) blocks as
// in round 1, but each wave now handles TWO nodes: all four row-loads are
// issued back-to-back (64 B/lane in flight, 2x round-1) before any use, and
// the two butterfly-reduction chains interleave. Tests the theory that proj
// is outstanding-request-bound (neither HBM nor L3 is saturated at 2.9 TB/s
// each in round-7 counters).
// ---------------------------------------------------------------------------
__global__ __launch_bounds__(256) void proj_kernel(
    const float* __restrict__ whr, const float* __restrict__ whi,
    const float* __restrict__ wr,  const float* __restrict__ wi,
    const float* __restrict__ br,  const float* __restrict__ bi,
    unsigned* __restrict__ tmp, int n_nodes)
{
    const int wid  = (int)((blockIdx.x * (unsigned)blockDim.x + threadIdx.x) >> 6);
    const int lane = threadIdx.x & 63;
    const int n0 = wid * 2;
    const int n1 = n0 + 1;
    if (n0 >= n_nodes) return;

    const float4 u = ((const float4*)wr)[lane];
    const float4 v = ((const float4*)wi)[lane];

    // Issue all row loads up front (4 dwordx4 per lane in flight).
    const float4 a0 = ((const float4*)(whr + (size_t)n0 * C_DIM))[lane];
    const float4 b0 = ((const float4*)(whi + (size_t)n0 * C_DIM))[lane];
    float4 a1, b1;
    const bool has1 = (n1 < n_nodes);
    if (has1) {
        a1 = ((const float4*)(whr + (size_t)n1 * C_DIM))[lane];
        b1 = ((const float4*)(whi + (size_t)n1 * C_DIM))[lane];
    }

    float vr0 = a0.x*u.x + a0.y*u.y + a0.z*u.z + a0.w*u.w
              - (b0.x*v.x + b0.y*v.y + b0.z*v.z + b0.w*v.w);
    float vi0 = a0.x*v.x + a0.y*v.y + a0.z*v.z + a0.w*v.w
              +  b0.x*u.x + b0.y*u.y + b0.z*u.z + b0.w*u.w;
    float vr1 = 0.f, vi1 = 0.f;
    if (has1) {
        vr1 = a1.x*u.x + a1.y*u.y + a1.z*u.z + a1.w*u.w
            - (b1.x*v.x + b1.y*v.y + b1.z*v.z + b1.w*v.w);
        vi1 = a1.x*v.x + a1.y*v.y + a1.z*v.z + a1.w*v.w
            +  b1.x*u.x + b1.y*u.y + b1.z*u.z + b1.w*u.w;
    }

    // Two interleaved butterfly chains — pipeline the cross-lane latency.
    #pragma unroll
    for (int off = 32; off > 0; off >>= 1) {
        vr0 += __shfl_xor(vr0, off, 64);
        vi0 += __shfl_xor(vi0, off, 64);
        vr1 += __shfl_xor(vr1, off, 64);
        vi1 += __shfl_xor(vi1, off, 64);
    }

    if (lane == 0) {
        const float br0 = br[0], bi0 = bi[0];
        tmp[n0] = bf16_rne(vr0 + br0) | (bf16_rne(vi0 + bi0) << 16);
        if (has1) {
            tmp[n1] = bf16_rne(vr1 + br0) | (bf16_rne(vi1 + bi0) << 16);
        }
    }
}

// ---------------------------------------------------------------------------
// Kernel B: per-column attention + normalization, one thread per column
// (round-1 structure; bf16x2-packed 400 KB gather table from round 7).
// ---------------------------------------------------------------------------
__global__ __launch_bounds__(256) void attn_kernel(
    const int* __restrict__ nneg, const unsigned* __restrict__ tmp,
    float* __restrict__ out, int m_cols)
{
    const int m = blockIdx.x * blockDim.x + threadIdx.x;
    if (m >= m_cols) return;

    const unsigned cp = tmp[nneg[m]];
    const float cr = __uint_as_float(cp << 16);
    const float ci = __uint_as_float(cp & 0xffff0000u);

    float att[K_NEIGH];
    float s = 0.f;
    #pragma unroll
    for (int k = 0; k < K_NEIGH; ++k) {
        const int idx = nneg[(size_t)(k + 1) * m_cols + m];
        const unsigned tp = tmp[idx];
        const float tr = __uint_as_float(tp << 16);
        const float ti = __uint_as_float(tp & 0xffff0000u);
        const float a = fmaxf(cr * tr + ci * ti, 0.f);
        att[k] = a;
        s += a;
    }

    const float r = 1.0f / (s + 0.001f);
    #pragma unroll
    for (int k = 0; k < K_NEIGH; ++k) {
        out[(size_t)k * m_cols + m] = att[k] * r;
    }
}

// ---------------------------------------------------------------------------
extern "C" void kernel_launch(void* const* d_in, const int* in_sizes, int n_in,
                              void* d_out, int out_size, void* d_ws, size_t ws_size,
                              hipStream_t stream)
{
    const float* whr = (const float*)d_in[0];
    const float* whi = (const float*)d_in[1];
    const int*   nng = (const int*)d_in[2];
    // d_in[3] = k_neighbors scalar (fixed = 32)
    const float* wr  = (const float*)d_in[4];
    const float* wi  = (const float*)d_in[5];
    const float* br  = (const float*)d_in[6];
    const float* bi  = (const float*)d_in[7];

    const int c_dim   = in_sizes[4];                 // 256
    const int n_nodes = in_sizes[0] / c_dim;         // 100000
    const int m_cols  = in_sizes[2] / (K_NEIGH + 1); // 100000

    unsigned* tmp = (unsigned*)d_ws;                 // 400 KB packed bf16x2

    // Kernel A: 2 nodes per wave, 8 nodes per 256-thread block.
    const int blocksA = (n_nodes + 7) / 8;
    proj_kernel<<<blocksA, 256, 0, stream>>>(whr, whi, wr, wi, br, bi, tmp, n_nodes);

    // Kernel B: one thread per column.
    const int blocksB = (m_cols + 255) / 256;
    attn_kernel<<<blocksB, 256, 0, stream>>>(nng, tmp, (float*)d_out, m_cols);
}